// Round 9
// baseline (294.730 us; speedup 1.0000x reference)
//
#include <hip/hip_runtime.h>

// ---------------------------------------------------------------------------
// multi_head_attention: B=2, S=2048, E=1024, H=16, HD=64, fp32 in/out.
// bf16 MFMA (16x16x32) everywhere, fp32 accumulate.
// R1: XOR-swizzled LDS staging, no-online-max softmax, permuted-key P/V.
// R2: fix gemm staging offset. R3: fused cvt. R4: vtrans fused into gemm_qkv.
// R5: attn phase-split K/V prefetch (single buffer), MFMA row-sum.
// R6: attn 32 q-rows/wave; exp2 path; coalesced gemm_qkv epilogue via LDS.
// R7: split-K z=2 REGRESSED (+25MB partials +12us combine for -3us attn) ->
//     reverted in R8.
// R8: gemm K-loops restructured to attn-R5 pattern: read all frags to regs,
//     barrier, THEN issue next tile's global_load_lds into the same buffers,
//     then MFMA on regs -- the vmcnt drain lands a full MFMA phase after
//     issue instead of immediately. launch_bounds(256,3) to keep 3 blocks/CU.
// ---------------------------------------------------------------------------

typedef __bf16 bf16x8 __attribute__((ext_vector_type(8)));
typedef __bf16 bf16x4 __attribute__((ext_vector_type(4)));
typedef float f32x4 __attribute__((ext_vector_type(4)));
typedef unsigned short ushort_t;

#define S_LEN 2048
#define E_DIM 1024
#define H_NUM 16
#define HD_DIM 64

#if __has_builtin(__builtin_amdgcn_exp2f)
#define EXP2(x) __builtin_amdgcn_exp2f(x)
#else
#define EXP2(x) __exp2f(x)
#endif

__device__ __forceinline__ ushort_t f2bf(float f) {
  union { float f; unsigned u; } v; v.f = f;
  unsigned u = v.u;
  unsigned r = (u + 0x7FFFu + ((u >> 16) & 1u)) >> 16;  // RNE
  return (ushort_t)r;
}

#define GLDS16(gp, lp)                                              \
  __builtin_amdgcn_global_load_lds(                                 \
      (const __attribute__((address_space(1))) unsigned int*)(gp),  \
      (__attribute__((address_space(3))) unsigned int*)(lp), 16, 0, 0)

// ---------------- fused fp32 -> bf16 converts (one kernel) ----------------
__global__ __launch_bounds__(256) void cvt_all(
    const float* __restrict__ X, const float* __restrict__ Wq,
    const float* __restrict__ Wk, const float* __restrict__ Wv,
    const float* __restrict__ Wo, ushort_t* __restrict__ Xbf,
    ushort_t* __restrict__ Wqkv, ushort_t* __restrict__ Wob) {
  int i = blockIdx.x * 256 + threadIdx.x;
  const float* src;
  ushort_t* dst;
  int off;
  if (i < 1048576) {
    src = X; dst = Xbf; off = i;
  } else if (i < 1310720) {
    src = Wq; dst = Wqkv; off = i - 1048576;
  } else if (i < 1572864) {
    src = Wk; dst = Wqkv + (1 << 20); off = i - 1310720;
  } else if (i < 1835008) {
    src = Wv; dst = Wqkv + (2 << 20); off = i - 1572864;
  } else {
    src = Wo; dst = Wob; off = i - 1835008;
  }
  float4 v = ((const float4*)src)[off];
  ushort4 o;
  o.x = f2bf(v.x); o.y = f2bf(v.y); o.z = f2bf(v.z); o.w = f2bf(v.w);
  ((ushort4*)dst)[off] = o;
}

// ---------------- fused QKV projection gemm (BK=64, swizzled) ----------------
// A = Xbf [4096][1024], B = Wqkv [3][1024][1024] (row = out col, k contig)
// grid: 768 blocks 1D, group-swizzled (G=8 m-tiles x 24 n-tiles per group).
// K-loop: frag-read -> barrier -> prefetch-next -> MFMA (drain hidden).
__global__ __launch_bounds__(256, 3) void gemm_qkv(
    const ushort_t* __restrict__ Xbf, const ushort_t* __restrict__ Wqkv,
    const float* __restrict__ bq, const float* __restrict__ bk,
    const float* __restrict__ bv,
    ushort_t* __restrict__ Qb, ushort_t* __restrict__ Kb,
    ushort_t* __restrict__ Vt) {
  __shared__ ushort_t smem[16384];  // As | Bs; reused as 128x128 C tile (Ls)
  ushort_t* As = smem;
  ushort_t* Bs = smem + 8192;
  const int t = threadIdx.x;
  const int w = t >> 6, lane = t & 63, quad = lane >> 4, lr = lane & 15;
  const int bid = blockIdx.x;
  const int grp = bid / 192, rr = bid % 192;
  const int m0 = (grp * 8 + (rr & 7)) * 128, n0 = (rr >> 3) * 128;
  const int wm = (w & 1) * 64, wn = (w >> 1) * 64;
  const int matid = n0 >> 10;
  const int nl0 = n0 & 1023;

  const int srow = t >> 3;
  const int gsrc = (t & 7) ^ (srow & 7);
  const ushort_t* Ag = Xbf + (size_t)(m0 + srow) * E_DIM + gsrc * 8;
  const ushort_t* Bg = Wqkv + (size_t)matid * E_DIM * E_DIM +
                       (size_t)(nl0 + srow) * E_DIM + gsrc * 8;

  // prologue: stage tile 0
#pragma unroll
  for (int r = 0; r < 4; r++) {
    GLDS16(Ag + (size_t)r * 32 * E_DIM, As + r * 2048 + t * 8);
    GLDS16(Bg + (size_t)r * 32 * E_DIM, Bs + r * 2048 + t * 8);
  }
  Ag += 64; Bg += 64;

  f32x4 acc[4][4] = {};

  for (int kt = 0; kt < E_DIM / 64; ++kt) {
    __syncthreads();  // tile kt staged (drains prefetch issued last iter)
    bf16x8 af[2][4], bfr[2][4];
#pragma unroll
    for (int kk = 0; kk < 2; kk++) {
      const int gs0 = (kk * 4 + quad) ^ (lr & 7);
#pragma unroll
      for (int i = 0; i < 4; i++) {
        af[kk][i]  = *(const bf16x8*)(As + (wm + i * 16 + lr) * 64 + gs0 * 8);
        bfr[kk][i] = *(const bf16x8*)(Bs + (wn + i * 16 + lr) * 64 + gs0 * 8);
      }
    }
    __syncthreads();  // all waves' frag reads done (no vmcnt pending here)
    if (kt + 1 < E_DIM / 64) {
#pragma unroll
      for (int r = 0; r < 4; r++) {
        GLDS16(Ag + (size_t)r * 32 * E_DIM, As + r * 2048 + t * 8);
        GLDS16(Bg + (size_t)r * 32 * E_DIM, Bs + r * 2048 + t * 8);
      }
      Ag += 64; Bg += 64;
    }
    if (matid < 2) {
#pragma unroll
      for (int kk = 0; kk < 2; kk++)
#pragma unroll
        for (int i = 0; i < 4; i++)
#pragma unroll
          for (int j = 0; j < 4; j++)
            acc[i][j] = __builtin_amdgcn_mfma_f32_16x16x32_bf16(
                bfr[kk][j], af[kk][i], acc[i][j], 0, 0, 0);  // C^T
    } else {
#pragma unroll
      for (int kk = 0; kk < 2; kk++)
#pragma unroll
        for (int i = 0; i < 4; i++)
#pragma unroll
          for (int j = 0; j < 4; j++)
            acc[i][j] = __builtin_amdgcn_mfma_f32_16x16x32_bf16(
                af[kk][i], bfr[kk][j], acc[i][j], 0, 0, 0);
    }
  }

  const float* bias_p = (matid == 0) ? bq : (matid == 1) ? bk : bv;
  ushort_t* Ls = smem;
  if (matid < 2) {
    // acc[i][j] = C^T tile: row n = wn+j*16+quad*4+r, col m = wm+i*16+lr.
    ushort_t* dst = (matid == 0) ? Qb : Kb;
    const float scl = (matid == 0) ? 0.18033688f : 1.0f;  // 0.125*log2e
#pragma unroll
    for (int j = 0; j < 4; j++) {
      const int nb = wn + j * 16 + quad * 4;
      float b0 = bias_p[nl0 + nb], b1 = bias_p[nl0 + nb + 1];
      float b2 = bias_p[nl0 + nb + 2], b3 = bias_p[nl0 + nb + 3];
#pragma unroll
      for (int i = 0; i < 4; i++) {
        const int m = wm + i * 16 + lr;
        bf16x4 pv;
        pv[0] = (__bf16)((acc[i][j][0] + b0) * scl);
        pv[1] = (__bf16)((acc[i][j][1] + b1) * scl);
        pv[2] = (__bf16)((acc[i][j][2] + b2) * scl);
        pv[3] = (__bf16)((acc[i][j][3] + b3) * scl);
        *(bf16x4*)(Ls + m * 128 + (((nb >> 3) ^ (m & 7)) * 8) + (nb & 7)) = pv;
      }
    }
    __syncthreads();
#pragma unroll
    for (int it = 0; it < 8; it++) {
      const int task = t + 256 * it;
      const int m = task >> 4, g = task & 15;
      uint4 val = *(const uint4*)(Ls + m * 128 + ((g ^ (m & 7)) * 8));
      const int s = m0 + m, bb = s >> 11, ss = s & 2047;
      const int cl = nl0 + g * 8, h = cl >> 6, dd = cl & 63;
      *(uint4*)(dst + ((size_t)((bb * H_NUM + h) * S_LEN + ss)) * HD_DIM + dd) =
          val;
    }
  } else {
    // acc[i][j] = C tile: row m(s), col n(d). Stage Ls[n][m], b64 along m.
#pragma unroll
    for (int j = 0; j < 4; j++) {
      const int n = wn + j * 16 + lr;
      const float bias = bias_p[nl0 + n];
#pragma unroll
      for (int i = 0; i < 4; i++) {
        const int mb = wm + i * 16 + quad * 4;
        bf16x4 pv;
        pv[0] = (__bf16)(acc[i][j][0] + bias);
        pv[1] = (__bf16)(acc[i][j][1] + bias);
        pv[2] = (__bf16)(acc[i][j][2] + bias);
        pv[3] = (__bf16)(acc[i][j][3] + bias);
        *(bf16x4*)(Ls + n * 128 + (((mb >> 3) ^ (n & 7)) * 8) + (mb & 7)) = pv;
      }
    }
    __syncthreads();
    const int n = t & 127, grp2 = t >> 7;
    ushort_t v[64];
#pragma unroll
    for (int c = 0; c < 8; c++)
      *(uint4*)(v + c * 8) =
          *(const uint4*)(Ls + n * 128 + (((grp2 * 8 + c) ^ (n & 7)) * 8));
    const int cl = nl0 + n, h = cl >> 6, dd = cl & 63;
    const int sgb = m0 + grp2 * 64, bb = sgb >> 11, ssb = sgb & 2047;
    ushort_t* dstp =
        Vt + ((size_t)((bb * H_NUM + h) * HD_DIM + dd)) * S_LEN + ssb;
#pragma unroll
    for (int q = 0; q < 8; q++) {
      ushort_t o8[8];
#pragma unroll
      for (int u = 0; u < 8; u++) o8[u] = v[16 * (u & 3) + 2 * q + (u >> 2)];
      *(uint4*)(dstp + q * 8) = *(const uint4*)o8;
    }
  }
}

// ---------------- flash attention (q-tile 128, 32 q-rows/wave) -------------
// grid: x = 16 (128-q tiles), y = 32 (b*h), 256 thr (4 waves)
__global__ __launch_bounds__(256) void attn(
    const ushort_t* __restrict__ Qb, const ushort_t* __restrict__ Kb,
    const ushort_t* __restrict__ Vt, ushort_t* __restrict__ Ctx) {
  __shared__ ushort_t Ks[64 * 64];  // swizzled K tile
  __shared__ ushort_t Vs[64 * 64];  // swizzled V^T tile
  __shared__ ushort_t Ps[128 * 72]; // P rows (stride 72); Q staged flat first
  const int t = threadIdx.x, w = t >> 6, lane = t & 63;
  const int quad = lane >> 4, lr = lane & 15;
  const int bh = blockIdx.y, q0 = blockIdx.x * 128;
  const ushort_t* Qg = Qb + ((size_t)bh * S_LEN + q0) * HD_DIM;
  const ushort_t* Kg = Kb + (size_t)bh * S_LEN * HD_DIM;
  const ushort_t* Vg = Vt + (size_t)bh * HD_DIM * S_LEN;

  const int srow = t >> 3;                // staging LDS row (32-row chunks)
  const int gsrc = (t & 7) ^ (srow & 7);  // swizzled source granule

  // prologue: stage Q (flat into Ps, 128x64), K tile 0, V tile 0
#pragma unroll
  for (int r = 0; r < 4; r++)
    GLDS16(Qg + (size_t)(r * 32 + srow) * HD_DIM + gsrc * 8,
           Ps + r * 2048 + t * 8);
#pragma unroll
  for (int r = 0; r < 2; r++) {
    GLDS16(Kg + (size_t)(r * 32 + srow) * HD_DIM + gsrc * 8,
           Ks + r * 2048 + t * 8);
    GLDS16(Vg + (size_t)(r * 32 + srow) * S_LEN + gsrc * 8,
           Vs + r * 2048 + t * 8);
  }
  __syncthreads();
  bf16x8 qf[2][2];  // [mt][kc]; wave-private rows [32w, 32w+32)
#pragma unroll
  for (int mt = 0; mt < 2; mt++)
#pragma unroll
    for (int kc = 0; kc < 2; kc++) {
      int gs = (kc * 4 + quad) ^ (lr & 7);
      qf[mt][kc] =
          *(const bf16x8*)(Ps + (w * 32 + mt * 16 + lr) * 64 + gs * 8);
    }

  bf16x8 ones;
#pragma unroll
  for (int e = 0; e < 8; e++) ones[e] = (__bf16)1.0f;

  f32x4 cacc[2][4] = {};
  f32x4 lsum[2] = {};

  for (int kt = 0; kt < S_LEN / 64; ++kt) {
    // --- QK: S' = (Q*0.125*log2e) @ K^T ---
    f32x4 sacc[2][4] = {};
#pragma unroll
    for (int nt = 0; nt < 4; nt++) {
#pragma unroll
      for (int kc = 0; kc < 2; kc++) {
        int gs = (kc * 4 + quad) ^ (lr & 7);
        bf16x8 kf = *(const bf16x8*)(Ks + (nt * 16 + lr) * 64 + gs * 8);
        sacc[0][nt] = __builtin_amdgcn_mfma_f32_16x16x32_bf16(
            qf[0][kc], kf, sacc[0][nt], 0, 0, 0);
        sacc[1][nt] = __builtin_amdgcn_mfma_f32_16x16x32_bf16(
            qf[1][kc], kf, sacc[1][nt], 0, 0, 0);
      }
    }
    __syncthreads();  // barrier A: K reads done; drains prev V prefetch

    const int kn = (kt + 1) & (S_LEN / 64 - 1);
    // prefetch next K (hidden behind exp + PV)
#pragma unroll
    for (int r = 0; r < 2; r++)
      GLDS16(Kg + (size_t)(kn * 64 + r * 32 + srow) * HD_DIM + gsrc * 8,
             Ks + r * 2048 + t * 8);

    // --- softmax numerator: p = exp2(s'), packed b64 into wave-private Ps
#pragma unroll
    for (int mt = 0; mt < 2; mt++) {
#pragma unroll
      for (int i = 0; i < 4; i++) {
        float p0 = EXP2(sacc[mt][0][i]);
        float p1 = EXP2(sacc[mt][1][i]);
        float p2 = EXP2(sacc[mt][2][i]);
        float p3 = EXP2(sacc[mt][3][i]);
        bf16x4 pv;
        pv[0] = (__bf16)p0; pv[1] = (__bf16)p1;
        pv[2] = (__bf16)p2; pv[3] = (__bf16)p3;
        int row = w * 32 + mt * 16 + quad * 4 + i;
        *(bf16x4*)(Ps + row * 72 + lr * 4) = pv;
      }
    }

    // --- PV + MFMA row-sum; vf shared across mt ---
#pragma unroll
    for (int kc = 0; kc < 2; kc++) {
      int gs = (kc * 4 + quad) ^ (lr & 7);
      bf16x8 vf[4];
#pragma unroll
      for (int dt = 0; dt < 4; dt++)
        vf[dt] = *(const bf16x8*)(Vs + (dt * 16 + lr) * 64 + gs * 8);
#pragma unroll
      for (int mt = 0; mt < 2; mt++) {
        bf16x8 pf = *(const bf16x8*)(Ps + (w * 32 + mt * 16 + lr) * 72 +
                                     kc * 32 + quad * 8);
        lsum[mt] =
            __builtin_amdgcn_mfma_f32_16x16x32_bf16(pf, ones, lsum[mt], 0, 0, 0);
#pragma unroll
        for (int dt = 0; dt < 4; dt++)
          cacc[mt][dt] = __builtin_amdgcn_mfma_f32_16x16x32_bf16(
              pf, vf[dt], cacc[mt][dt], 0, 0, 0);
      }
    }
    __syncthreads();  // barrier B: V reads done; drains this iter's K prefetch

    // prefetch next V (hidden behind loop-back + next QK)
#pragma unroll
    for (int r = 0; r < 2; r++)
      GLDS16(Vg + (size_t)(r * 32 + srow) * S_LEN + kn * 64 + gsrc * 8,
             Vs + r * 2048 + t * 8);
  }

  // epilogue: lsum holds full row sums (identical across the 16 lanes)
#pragma unroll
  for (int mt = 0; mt < 2; mt++) {
#pragma unroll
    for (int i = 0; i < 4; i++) {
      float inv = 1.0f / lsum[mt][i];
      int srow2 = q0 + w * 32 + mt * 16 + quad * 4 + i;
#pragma unroll
      for (int dt = 0; dt < 4; dt++)
        Ctx[((size_t)bh * S_LEN + srow2) * HD_DIM + dt * 16 + lr] =
            f2bf(cacc[mt][dt][i] * inv);
    }
  }
}

// ---------------- output projection gemm (128x64 tiles, BK=64) --------------
// grid: 512 blocks 1D, group-swizzled (G=8 m-tiles x 16 n-tiles per group).
// Same frag-read -> barrier -> prefetch -> MFMA loop as gemm_qkv.
__global__ __launch_bounds__(256, 3) void gemm_out(
    const ushort_t* __restrict__ Cb, const ushort_t* __restrict__ Wob,
    const float* __restrict__ bo, float* __restrict__ out) {
  __shared__ ushort_t As[128 * 64];
  __shared__ ushort_t Bs[64 * 64];
  const int t = threadIdx.x;
  const int w = t >> 6, lane = t & 63, quad = lane >> 4, lr = lane & 15;
  const int bid = blockIdx.x;
  const int grp = bid >> 7, rr = bid & 127;
  const int m0 = (grp * 8 + (rr & 7)) * 128, n0 = (rr >> 3) * 64;
  const int wm = (w & 1) * 64, wn = (w >> 1) * 32;

  const int srow = t >> 3;
  const int gsrc = (t & 7) ^ (srow & 7);
  const ushort_t* Ag = Cb + (size_t)(m0 + srow) * E_DIM + gsrc * 8;
  const ushort_t* Bg = Wob + (size_t)(n0 + srow) * E_DIM + gsrc * 8;

  // prologue: stage tile 0
#pragma unroll
  for (int r = 0; r < 4; r++)
    GLDS16(Ag + (size_t)r * 32 * E_DIM, As + r * 2048 + t * 8);
#pragma unroll
  for (int r = 0; r < 2; r++)
    GLDS16(Bg + (size_t)r * 32 * E_DIM, Bs + r * 2048 + t * 8);
  Ag += 64; Bg += 64;

  f32x4 acc[4][2] = {};

  for (int kt = 0; kt < E_DIM / 64; ++kt) {
    __syncthreads();  // tile kt staged
    bf16x8 af[2][4], bfr[2][2];
#pragma unroll
    for (int kk = 0; kk < 2; kk++) {
      const int gs0 = (kk * 4 + quad) ^ (lr & 7);
#pragma unroll
      for (int i = 0; i < 4; i++)
        af[kk][i] = *(const bf16x8*)(As + (wm + i * 16 + lr) * 64 + gs0 * 8);
#pragma unroll
      for (int j = 0; j < 2; j++)
        bfr[kk][j] = *(const bf16x8*)(Bs + (wn + j * 16 + lr) * 64 + gs0 * 8);
    }
    __syncthreads();  // reads done
    if (kt + 1 < E_DIM / 64) {
#pragma unroll
      for (int r = 0; r < 4; r++)
        GLDS16(Ag + (size_t)r * 32 * E_DIM, As + r * 2048 + t * 8);
#pragma unroll
      for (int r = 0; r < 2; r++)
        GLDS16(Bg + (size_t)r * 32 * E_DIM, Bs + r * 2048 + t * 8);
      Ag += 64; Bg += 64;
    }
#pragma unroll
    for (int kk = 0; kk < 2; kk++)
#pragma unroll
      for (int i = 0; i < 4; i++)
#pragma unroll
        for (int j = 0; j < 2; j++)
          acc[i][j] = __builtin_amdgcn_mfma_f32_16x16x32_bf16(
              af[kk][i], bfr[kk][j], acc[i][j], 0, 0, 0);
  }

#pragma unroll
  for (int j = 0; j < 2; j++) {
    int col = n0 + wn + j * 16 + lr;
    float bias = bo[col];
#pragma unroll
    for (int i = 0; i < 4; i++) {
#pragma unroll
      for (int r = 0; r < 4; r++) {
        int row = m0 + wm + i * 16 + quad * 4 + r;
        out[(size_t)row * E_DIM + col] = acc[i][j][r] + bias;
      }
    }
  }
}

// ---------------- launch ----------------
extern "C" void kernel_launch(void* const* d_in, const int* in_sizes, int n_in,
                              void* d_out, int out_size, void* d_ws,
                              size_t ws_size, hipStream_t stream) {
  const float* X  = (const float*)d_in[0];
  const float* bq = (const float*)d_in[2];
  const float* bk = (const float*)d_in[4];
  const float* bv = (const float*)d_in[6];
  const float* Wo = (const float*)d_in[7];
  const float* bo = (const float*)d_in[8];
  float* out = (float*)d_out;

  char* ws = (char*)d_ws;
  ushort_t* Xbf  = (ushort_t*)(ws);                       // 8 MB
  ushort_t* Wqkv = (ushort_t*)(ws + ((size_t)8 << 20));   // 6 MB
  ushort_t* Wob  = (ushort_t*)(ws + ((size_t)14 << 20));  // 2 MB
  ushort_t* Qb   = (ushort_t*)(ws + ((size_t)16 << 20));  // 8 MB
  ushort_t* Kb   = (ushort_t*)(ws + ((size_t)24 << 20));  // 8 MB
  ushort_t* Vt   = (ushort_t*)(ws + ((size_t)32 << 20));  // 8 MB
  ushort_t* Cb   = (ushort_t*)(ws + ((size_t)40 << 20));  // 8 MB (48 MB total)

  cvt_all<<<8192, 256, 0, stream>>>(X, (const float*)d_in[1],
                                    (const float*)d_in[3],
                                    (const float*)d_in[5], Wo, Xbf, Wqkv, Wob);

  gemm_qkv<<<768, 256, 0, stream>>>(Xbf, Wqkv, bq, bk, bv, Qb, Kb, Vt);
  attn<<<dim3(16, 32), 256, 0, stream>>>(Qb, Kb, Vt, Cb);
  gemm_out<<<512, 256, 0, stream>>>(Cb, Wob, bo, out);
}

// Round 10
// 198.150 us; speedup vs baseline: 1.4874x; 1.4874x over previous
//
#include <hip/hip_runtime.h>

// ---------------------------------------------------------------------------
// multi_head_attention: B=2, S=2048, E=1024, H=16, HD=64, fp32 in/out.
// bf16 MFMA (16x16x32) everywhere, fp32 accumulate.
// R1: XOR-swizzled LDS staging, no-online-max softmax, permuted-key P/V.
// R2: fix gemm staging offset. R3: fused cvt. R4: vtrans fused into gemm_qkv.
// R5: attn phase-split K/V prefetch (single buffer), MFMA row-sum.
// R6: attn 32 q-rows/wave; exp2 path; coalesced gemm_qkv epilogue via LDS.
// R7: split-K REGRESSED (reverted). R8: frag-read+prefetch K-loop with
//     launch_bounds cap REGRESSED HARD (VGPR 84 -> scratch spills, 430MB
//     writes) -> reverted.
// R9: gemms back to R7 K-loop (stage -> barrier -> read+MFMA -> barrier),
//     plain launch_bounds(256). gemm_out back to 64x64 tiles / 1024 blocks
//     (R5 vs R6 A/B showed 512-block 128x64 cost ~18us: 2 blocks/CU can't
//     hide the staging drain), now with group swizzle.
// ---------------------------------------------------------------------------

typedef __bf16 bf16x8 __attribute__((ext_vector_type(8)));
typedef __bf16 bf16x4 __attribute__((ext_vector_type(4)));
typedef float f32x4 __attribute__((ext_vector_type(4)));
typedef unsigned short ushort_t;

#define S_LEN 2048
#define E_DIM 1024
#define H_NUM 16
#define HD_DIM 64

#if __has_builtin(__builtin_amdgcn_exp2f)
#define EXP2(x) __builtin_amdgcn_exp2f(x)
#else
#define EXP2(x) __exp2f(x)
#endif

__device__ __forceinline__ ushort_t f2bf(float f) {
  union { float f; unsigned u; } v; v.f = f;
  unsigned u = v.u;
  unsigned r = (u + 0x7FFFu + ((u >> 16) & 1u)) >> 16;  // RNE
  return (ushort_t)r;
}

#define GLDS16(gp, lp)                                              \
  __builtin_amdgcn_global_load_lds(                                 \
      (const __attribute__((address_space(1))) unsigned int*)(gp),  \
      (__attribute__((address_space(3))) unsigned int*)(lp), 16, 0, 0)

// ---------------- fused fp32 -> bf16 converts (one kernel) ----------------
__global__ __launch_bounds__(256) void cvt_all(
    const float* __restrict__ X, const float* __restrict__ Wq,
    const float* __restrict__ Wk, const float* __restrict__ Wv,
    const float* __restrict__ Wo, ushort_t* __restrict__ Xbf,
    ushort_t* __restrict__ Wqkv, ushort_t* __restrict__ Wob) {
  int i = blockIdx.x * 256 + threadIdx.x;
  const float* src;
  ushort_t* dst;
  int off;
  if (i < 1048576) {
    src = X; dst = Xbf; off = i;
  } else if (i < 1310720) {
    src = Wq; dst = Wqkv; off = i - 1048576;
  } else if (i < 1572864) {
    src = Wk; dst = Wqkv + (1 << 20); off = i - 1310720;
  } else if (i < 1835008) {
    src = Wv; dst = Wqkv + (2 << 20); off = i - 1572864;
  } else {
    src = Wo; dst = Wob; off = i - 1835008;
  }
  float4 v = ((const float4*)src)[off];
  ushort4 o;
  o.x = f2bf(v.x); o.y = f2bf(v.y); o.z = f2bf(v.z); o.w = f2bf(v.w);
  ((ushort4*)dst)[off] = o;
}

// ---------------- fused QKV projection gemm (BK=64, swizzled) ----------------
// A = Xbf [4096][1024], B = Wqkv [3][1024][1024] (row = out col, k contig)
// grid: 768 blocks 1D, group-swizzled (G=8 m-tiles x 24 n-tiles per group).
__global__ __launch_bounds__(256) void gemm_qkv(
    const ushort_t* __restrict__ Xbf, const ushort_t* __restrict__ Wqkv,
    const float* __restrict__ bq, const float* __restrict__ bk,
    const float* __restrict__ bv,
    ushort_t* __restrict__ Qb, ushort_t* __restrict__ Kb,
    ushort_t* __restrict__ Vt) {
  __shared__ ushort_t smem[16384];  // As | Bs; reused as 128x128 C tile (Ls)
  ushort_t* As = smem;
  ushort_t* Bs = smem + 8192;
  const int t = threadIdx.x;
  const int w = t >> 6, lane = t & 63, quad = lane >> 4, lr = lane & 15;
  const int bid = blockIdx.x;
  const int grp = bid / 192, rr = bid % 192;
  const int m0 = (grp * 8 + (rr & 7)) * 128, n0 = (rr >> 3) * 128;
  const int wm = (w & 1) * 64, wn = (w >> 1) * 64;
  const int matid = n0 >> 10;
  const int nl0 = n0 & 1023;

  const int srow = t >> 3;
  const int gsrc = (t & 7) ^ (srow & 7);
  const ushort_t* Ag = Xbf + (size_t)(m0 + srow) * E_DIM + gsrc * 8;
  const ushort_t* Bg = Wqkv + (size_t)matid * E_DIM * E_DIM +
                       (size_t)(nl0 + srow) * E_DIM + gsrc * 8;

  f32x4 acc[4][4] = {};

  for (int kt = 0; kt < E_DIM / 64; ++kt) {
#pragma unroll
    for (int r = 0; r < 4; r++) {
      GLDS16(Ag + (size_t)r * 32 * E_DIM, As + r * 2048 + t * 8);
      GLDS16(Bg + (size_t)r * 32 * E_DIM, Bs + r * 2048 + t * 8);
    }
    Ag += 64; Bg += 64;
    __syncthreads();
#pragma unroll
    for (int kk = 0; kk < 2; kk++) {
      bf16x8 af[4], bfr[4];
      const int gs0 = (kk * 4 + quad) ^ (lr & 7);
#pragma unroll
      for (int i = 0; i < 4; i++) {
        af[i]  = *(const bf16x8*)(As + (wm + i * 16 + lr) * 64 + gs0 * 8);
        bfr[i] = *(const bf16x8*)(Bs + (wn + i * 16 + lr) * 64 + gs0 * 8);
      }
      if (matid < 2) {
#pragma unroll
        for (int i = 0; i < 4; i++)
#pragma unroll
          for (int j = 0; j < 4; j++)
            acc[i][j] = __builtin_amdgcn_mfma_f32_16x16x32_bf16(
                bfr[j], af[i], acc[i][j], 0, 0, 0);  // C^T
      } else {
#pragma unroll
        for (int i = 0; i < 4; i++)
#pragma unroll
          for (int j = 0; j < 4; j++)
            acc[i][j] = __builtin_amdgcn_mfma_f32_16x16x32_bf16(
                af[i], bfr[j], acc[i][j], 0, 0, 0);
      }
    }
    __syncthreads();
  }

  const float* bias_p = (matid == 0) ? bq : (matid == 1) ? bk : bv;
  ushort_t* Ls = smem;
  if (matid < 2) {
    // acc[i][j] = C^T tile: row n = wn+j*16+quad*4+r, col m = wm+i*16+lr.
    ushort_t* dst = (matid == 0) ? Qb : Kb;
    const float scl = (matid == 0) ? 0.18033688f : 1.0f;  // 0.125*log2e
#pragma unroll
    for (int j = 0; j < 4; j++) {
      const int nb = wn + j * 16 + quad * 4;
      float b0 = bias_p[nl0 + nb], b1 = bias_p[nl0 + nb + 1];
      float b2 = bias_p[nl0 + nb + 2], b3 = bias_p[nl0 + nb + 3];
#pragma unroll
      for (int i = 0; i < 4; i++) {
        const int m = wm + i * 16 + lr;
        bf16x4 pv;
        pv[0] = (__bf16)((acc[i][j][0] + b0) * scl);
        pv[1] = (__bf16)((acc[i][j][1] + b1) * scl);
        pv[2] = (__bf16)((acc[i][j][2] + b2) * scl);
        pv[3] = (__bf16)((acc[i][j][3] + b3) * scl);
        *(bf16x4*)(Ls + m * 128 + (((nb >> 3) ^ (m & 7)) * 8) + (nb & 7)) = pv;
      }
    }
    __syncthreads();
#pragma unroll
    for (int it = 0; it < 8; it++) {
      const int task = t + 256 * it;
      const int m = task >> 4, g = task & 15;
      uint4 val = *(const uint4*)(Ls + m * 128 + ((g ^ (m & 7)) * 8));
      const int s = m0 + m, bb = s >> 11, ss = s & 2047;
      const int cl = nl0 + g * 8, h = cl >> 6, dd = cl & 63;
      *(uint4*)(dst + ((size_t)((bb * H_NUM + h) * S_LEN + ss)) * HD_DIM + dd) =
          val;
    }
  } else {
    // acc[i][j] = C tile: row m(s), col n(d). Stage Ls[n][m], b64 along m.
#pragma unroll
    for (int j = 0; j < 4; j++) {
      const int n = wn + j * 16 + lr;
      const float bias = bias_p[nl0 + n];
#pragma unroll
      for (int i = 0; i < 4; i++) {
        const int mb = wm + i * 16 + quad * 4;
        bf16x4 pv;
        pv[0] = (__bf16)(acc[i][j][0] + bias);
        pv[1] = (__bf16)(acc[i][j][1] + bias);
        pv[2] = (__bf16)(acc[i][j][2] + bias);
        pv[3] = (__bf16)(acc[i][j][3] + bias);
        *(bf16x4*)(Ls + n * 128 + (((mb >> 3) ^ (n & 7)) * 8) + (mb & 7)) = pv;
      }
    }
    __syncthreads();
    const int n = t & 127, grp2 = t >> 7;
    ushort_t v[64];
#pragma unroll
    for (int c = 0; c < 8; c++)
      *(uint4*)(v + c * 8) =
          *(const uint4*)(Ls + n * 128 + (((grp2 * 8 + c) ^ (n & 7)) * 8));
    const int cl = nl0 + n, h = cl >> 6, dd = cl & 63;
    const int sgb = m0 + grp2 * 64, bb = sgb >> 11, ssb = sgb & 2047;
    ushort_t* dstp =
        Vt + ((size_t)((bb * H_NUM + h) * HD_DIM + dd)) * S_LEN + ssb;
#pragma unroll
    for (int q = 0; q < 8; q++) {
      ushort_t o8[8];
#pragma unroll
      for (int u = 0; u < 8; u++) o8[u] = v[16 * (u & 3) + 2 * q + (u >> 2)];
      *(uint4*)(dstp + q * 8) = *(const uint4*)o8;
    }
  }
}

// ---------------- flash attention (q-tile 128, 32 q-rows/wave) -------------
// grid: x = 16 (128-q tiles), y = 32 (b*h), 256 thr (4 waves)
__global__ __launch_bounds__(256) void attn(
    const ushort_t* __restrict__ Qb, const ushort_t* __restrict__ Kb,
    const ushort_t* __restrict__ Vt, ushort_t* __restrict__ Ctx) {
  __shared__ ushort_t Ks[64 * 64];  // swizzled K tile
  __shared__ ushort_t Vs[64 * 64];  // swizzled V^T tile
  __shared__ ushort_t Ps[128 * 72]; // P rows (stride 72); Q staged flat first
  const int t = threadIdx.x, w = t >> 6, lane = t & 63;
  const int quad = lane >> 4, lr = lane & 15;
  const int bh = blockIdx.y, q0 = blockIdx.x * 128;
  const ushort_t* Qg = Qb + ((size_t)bh * S_LEN + q0) * HD_DIM;
  const ushort_t* Kg = Kb + (size_t)bh * S_LEN * HD_DIM;
  const ushort_t* Vg = Vt + (size_t)bh * HD_DIM * S_LEN;

  const int srow = t >> 3;                // staging LDS row (32-row chunks)
  const int gsrc = (t & 7) ^ (srow & 7);  // swizzled source granule

  // prologue: stage Q (flat into Ps, 128x64), K tile 0, V tile 0
#pragma unroll
  for (int r = 0; r < 4; r++)
    GLDS16(Qg + (size_t)(r * 32 + srow) * HD_DIM + gsrc * 8,
           Ps + r * 2048 + t * 8);
#pragma unroll
  for (int r = 0; r < 2; r++) {
    GLDS16(Kg + (size_t)(r * 32 + srow) * HD_DIM + gsrc * 8,
           Ks + r * 2048 + t * 8);
    GLDS16(Vg + (size_t)(r * 32 + srow) * S_LEN + gsrc * 8,
           Vs + r * 2048 + t * 8);
  }
  __syncthreads();
  bf16x8 qf[2][2];  // [mt][kc]; wave-private rows [32w, 32w+32)
#pragma unroll
  for (int mt = 0; mt < 2; mt++)
#pragma unroll
    for (int kc = 0; kc < 2; kc++) {
      int gs = (kc * 4 + quad) ^ (lr & 7);
      qf[mt][kc] =
          *(const bf16x8*)(Ps + (w * 32 + mt * 16 + lr) * 64 + gs * 8);
    }

  bf16x8 ones;
#pragma unroll
  for (int e = 0; e < 8; e++) ones[e] = (__bf16)1.0f;

  f32x4 cacc[2][4] = {};
  f32x4 lsum[2] = {};

  for (int kt = 0; kt < S_LEN / 64; ++kt) {
    // --- QK: S' = (Q*0.125*log2e) @ K^T ---
    f32x4 sacc[2][4] = {};
#pragma unroll
    for (int nt = 0; nt < 4; nt++) {
#pragma unroll
      for (int kc = 0; kc < 2; kc++) {
        int gs = (kc * 4 + quad) ^ (lr & 7);
        bf16x8 kf = *(const bf16x8*)(Ks + (nt * 16 + lr) * 64 + gs * 8);
        sacc[0][nt] = __builtin_amdgcn_mfma_f32_16x16x32_bf16(
            qf[0][kc], kf, sacc[0][nt], 0, 0, 0);
        sacc[1][nt] = __builtin_amdgcn_mfma_f32_16x16x32_bf16(
            qf[1][kc], kf, sacc[1][nt], 0, 0, 0);
      }
    }
    __syncthreads();  // barrier A: K reads done; drains prev V prefetch

    const int kn = (kt + 1) & (S_LEN / 64 - 1);
    // prefetch next K (hidden behind exp + PV)
#pragma unroll
    for (int r = 0; r < 2; r++)
      GLDS16(Kg + (size_t)(kn * 64 + r * 32 + srow) * HD_DIM + gsrc * 8,
             Ks + r * 2048 + t * 8);

    // --- softmax numerator: p = exp2(s'), packed b64 into wave-private Ps
#pragma unroll
    for (int mt = 0; mt < 2; mt++) {
#pragma unroll
      for (int i = 0; i < 4; i++) {
        float p0 = EXP2(sacc[mt][0][i]);
        float p1 = EXP2(sacc[mt][1][i]);
        float p2 = EXP2(sacc[mt][2][i]);
        float p3 = EXP2(sacc[mt][3][i]);
        bf16x4 pv;
        pv[0] = (__bf16)p0; pv[1] = (__bf16)p1;
        pv[2] = (__bf16)p2; pv[3] = (__bf16)p3;
        int row = w * 32 + mt * 16 + quad * 4 + i;
        *(bf16x4*)(Ps + row * 72 + lr * 4) = pv;
      }
    }

    // --- PV + MFMA row-sum; vf shared across mt ---
#pragma unroll
    for (int kc = 0; kc < 2; kc++) {
      int gs = (kc * 4 + quad) ^ (lr & 7);
      bf16x8 vf[4];
#pragma unroll
      for (int dt = 0; dt < 4; dt++)
        vf[dt] = *(const bf16x8*)(Vs + (dt * 16 + lr) * 64 + gs * 8);
#pragma unroll
      for (int mt = 0; mt < 2; mt++) {
        bf16x8 pf = *(const bf16x8*)(Ps + (w * 32 + mt * 16 + lr) * 72 +
                                     kc * 32 + quad * 8);
        lsum[mt] =
            __builtin_amdgcn_mfma_f32_16x16x32_bf16(pf, ones, lsum[mt], 0, 0, 0);
#pragma unroll
        for (int dt = 0; dt < 4; dt++)
          cacc[mt][dt] = __builtin_amdgcn_mfma_f32_16x16x32_bf16(
              pf, vf[dt], cacc[mt][dt], 0, 0, 0);
      }
    }
    __syncthreads();  // barrier B: V reads done; drains this iter's K prefetch

    // prefetch next V (hidden behind loop-back + next QK)
#pragma unroll
    for (int r = 0; r < 2; r++)
      GLDS16(Vg + (size_t)(r * 32 + srow) * S_LEN + kn * 64 + gsrc * 8,
             Vs + r * 2048 + t * 8);
  }

  // epilogue: lsum holds full row sums (identical across the 16 lanes)
#pragma unroll
  for (int mt = 0; mt < 2; mt++) {
#pragma unroll
    for (int i = 0; i < 4; i++) {
      float inv = 1.0f / lsum[mt][i];
      int srow2 = q0 + w * 32 + mt * 16 + quad * 4 + i;
#pragma unroll
      for (int dt = 0; dt < 4; dt++)
        Ctx[((size_t)bh * S_LEN + srow2) * HD_DIM + dt * 16 + lr] =
            f2bf(cacc[mt][dt][i] * inv);
    }
  }
}

// ---------------- output projection gemm (64x64 tiles, BK=64) ----------------
// grid: 1024 blocks 1D (4/CU), group-swizzled (8 m-tiles x 16 n-tiles/group)
__global__ __launch_bounds__(256) void gemm_out(
    const ushort_t* __restrict__ Cb, const ushort_t* __restrict__ Wob,
    const float* __restrict__ bo, float* __restrict__ out) {
  __shared__ ushort_t As[64 * 64];
  __shared__ ushort_t Bs[64 * 64];
  const int t = threadIdx.x;
  const int w = t >> 6, lane = t & 63, quad = lane >> 4, lr = lane & 15;
  const int bid = blockIdx.x;
  const int grp = bid >> 7, rr = bid & 127;  // 8 groups x (8m x 16n)
  const int m0 = (grp * 8 + (rr & 7)) * 64, n0 = (rr >> 3) * 64;
  const int wm = (w & 1) * 32, wn = (w >> 1) * 32;

  const int srow = t >> 3;
  const int gsrc = (t & 7) ^ (srow & 7);
  const ushort_t* Ag = Cb + (size_t)(m0 + srow) * E_DIM + gsrc * 8;
  const ushort_t* Bg = Wob + (size_t)(n0 + srow) * E_DIM + gsrc * 8;

  f32x4 acc[2][2] = {};

  for (int kt = 0; kt < E_DIM / 64; ++kt) {
#pragma unroll
    for (int r = 0; r < 2; r++) {
      GLDS16(Ag + (size_t)r * 32 * E_DIM, As + r * 2048 + t * 8);
      GLDS16(Bg + (size_t)r * 32 * E_DIM, Bs + r * 2048 + t * 8);
    }
    Ag += 64; Bg += 64;
    __syncthreads();
#pragma unroll
    for (int kk = 0; kk < 2; kk++) {
      bf16x8 af[2], bfr[2];
      const int gs0 = (kk * 4 + quad) ^ (lr & 7);
#pragma unroll
      for (int i = 0; i < 2; i++) {
        af[i]  = *(const bf16x8*)(As + (wm + i * 16 + lr) * 64 + gs0 * 8);
        bfr[i] = *(const bf16x8*)(Bs + (wn + i * 16 + lr) * 64 + gs0 * 8);
      }
#pragma unroll
      for (int i = 0; i < 2; i++)
#pragma unroll
        for (int j = 0; j < 2; j++)
          acc[i][j] = __builtin_amdgcn_mfma_f32_16x16x32_bf16(
              af[i], bfr[j], acc[i][j], 0, 0, 0);
    }
    __syncthreads();
  }

#pragma unroll
  for (int j = 0; j < 2; j++) {
    int col = n0 + wn + j * 16 + lr;
    float bias = bo[col];
#pragma unroll
    for (int i = 0; i < 2; i++) {
#pragma unroll
      for (int r = 0; r < 4; r++) {
        int row = m0 + wm + i * 16 + quad * 4 + r;
        out[(size_t)row * E_DIM + col] = acc[i][j][r] + bias;
      }
    }
  }
}

// ---------------- launch ----------------
extern "C" void kernel_launch(void* const* d_in, const int* in_sizes, int n_in,
                              void* d_out, int out_size, void* d_ws,
                              size_t ws_size, hipStream_t stream) {
  const float* X  = (const float*)d_in[0];
  const float* bq = (const float*)d_in[2];
  const float* bk = (const float*)d_in[4];
  const float* bv = (const float*)d_in[6];
  const float* Wo = (const float*)d_in[7];
  const float* bo = (const float*)d_in[8];
  float* out = (float*)d_out;

  char* ws = (char*)d_ws;
  ushort_t* Xbf  = (ushort_t*)(ws);                       // 8 MB
  ushort_t* Wqkv = (ushort_t*)(ws + ((size_t)8 << 20));   // 6 MB
  ushort_t* Wob  = (ushort_t*)(ws + ((size_t)14 << 20));  // 2 MB
  ushort_t* Qb   = (ushort_t*)(ws + ((size_t)16 << 20));  // 8 MB
  ushort_t* Kb   = (ushort_t*)(ws + ((size_t)24 << 20));  // 8 MB
  ushort_t* Vt   = (ushort_t*)(ws + ((size_t)32 << 20));  // 8 MB
  ushort_t* Cb   = (ushort_t*)(ws + ((size_t)40 << 20));  // 8 MB (48 MB total)

  cvt_all<<<8192, 256, 0, stream>>>(X, (const float*)d_in[1],
                                    (const float*)d_in[3],
                                    (const float*)d_in[5], Wo, Xbf, Wqkv, Wob);

  gemm_qkv<<<768, 256, 0, stream>>>(Xbf, Wqkv, bq, bk, bv, Qb, Kb, Vt);
  attn<<<dim3(16, 32), 256, 0, stream>>>(Qb, Kb, Vt, Cb);
  gemm_out<<<1024, 256, 0, stream>>>(Cb, Wob, bo, out);
}

// Round 11
// 195.246 us; speedup vs baseline: 1.5095x; 1.0149x over previous
//
#include <hip/hip_runtime.h>

// ---------------------------------------------------------------------------
// multi_head_attention: B=2, S=2048, E=1024, H=16, HD=64, fp32 in/out.
// bf16 MFMA (16x16x32) everywhere, fp32 accumulate.
// R1: XOR-swizzled LDS staging, no-online-max softmax, permuted-key P/V.
// R2: fix gemm staging offset. R3: fused cvt. R4: vtrans fused into gemm_qkv.
// R5: attn phase-split K/V prefetch (single buffer), MFMA row-sum.
// R6: attn 32 q-rows/wave; exp2 path; coalesced gemm_qkv epilogue via LDS.
// R7: split-K REGRESSED (reverted). R8: frag-read+launch_bounds cap spilled
//     (reverted). R9/R10: stable 198us; attn FETCH 71.7MB vs 24MB unique ->
//     K/V thrash every XCD's L2 (q-tiles of one bh round-robin across XCDs).
// R11: XCD-locality block swizzles (xcd = bid%8 assumption):
//     attn: all 16 q-tiles of a bh on one XCD (4bh x 512KB = 2MB/XCD L2);
//     gemm_qkv: 8m x 12n super-blocks per XCD (A 2MB + B 3MB);
//     gemm_out: 8m x 16n per XCD (A 1MB + Wo 2MB). Index-only change.
// ---------------------------------------------------------------------------

typedef __bf16 bf16x8 __attribute__((ext_vector_type(8)));
typedef __bf16 bf16x4 __attribute__((ext_vector_type(4)));
typedef float f32x4 __attribute__((ext_vector_type(4)));
typedef unsigned short ushort_t;

#define S_LEN 2048
#define E_DIM 1024
#define H_NUM 16
#define HD_DIM 64

#if __has_builtin(__builtin_amdgcn_exp2f)
#define EXP2(x) __builtin_amdgcn_exp2f(x)
#else
#define EXP2(x) __exp2f(x)
#endif

__device__ __forceinline__ ushort_t f2bf(float f) {
  union { float f; unsigned u; } v; v.f = f;
  unsigned u = v.u;
  unsigned r = (u + 0x7FFFu + ((u >> 16) & 1u)) >> 16;  // RNE
  return (ushort_t)r;
}

#define GLDS16(gp, lp)                                              \
  __builtin_amdgcn_global_load_lds(                                 \
      (const __attribute__((address_space(1))) unsigned int*)(gp),  \
      (__attribute__((address_space(3))) unsigned int*)(lp), 16, 0, 0)

// ---------------- fused fp32 -> bf16 converts (one kernel) ----------------
__global__ __launch_bounds__(256) void cvt_all(
    const float* __restrict__ X, const float* __restrict__ Wq,
    const float* __restrict__ Wk, const float* __restrict__ Wv,
    const float* __restrict__ Wo, ushort_t* __restrict__ Xbf,
    ushort_t* __restrict__ Wqkv, ushort_t* __restrict__ Wob) {
  int i = blockIdx.x * 256 + threadIdx.x;
  const float* src;
  ushort_t* dst;
  int off;
  if (i < 1048576) {
    src = X; dst = Xbf; off = i;
  } else if (i < 1310720) {
    src = Wq; dst = Wqkv; off = i - 1048576;
  } else if (i < 1572864) {
    src = Wk; dst = Wqkv + (1 << 20); off = i - 1310720;
  } else if (i < 1835008) {
    src = Wv; dst = Wqkv + (2 << 20); off = i - 1572864;
  } else {
    src = Wo; dst = Wob; off = i - 1835008;
  }
  float4 v = ((const float4*)src)[off];
  ushort4 o;
  o.x = f2bf(v.x); o.y = f2bf(v.y); o.z = f2bf(v.z); o.w = f2bf(v.w);
  ((ushort4*)dst)[off] = o;
}

// ---------------- fused QKV projection gemm (BK=64, swizzled) ----------------
// A = Xbf [4096][1024], B = Wqkv [3][1024][1024] (row = out col, k contig)
// grid: 768 blocks 1D. XCD swizzle: xcd k owns an 8m x 12n super-block.
__global__ __launch_bounds__(256) void gemm_qkv(
    const ushort_t* __restrict__ Xbf, const ushort_t* __restrict__ Wqkv,
    const float* __restrict__ bq, const float* __restrict__ bk,
    const float* __restrict__ bv,
    ushort_t* __restrict__ Qb, ushort_t* __restrict__ Kb,
    ushort_t* __restrict__ Vt) {
  __shared__ ushort_t smem[16384];  // As | Bs; reused as 128x128 C tile (Ls)
  ushort_t* As = smem;
  ushort_t* Bs = smem + 8192;
  const int t = threadIdx.x;
  const int w = t >> 6, lane = t & 63, quad = lane >> 4, lr = lane & 15;
  const int bid = blockIdx.x;
  const int k8 = bid & 7, u = bid >> 3;  // u in [0,96)
  const int m0 = ((k8 >> 1) * 8 + (u & 7)) * 128;   // m-tile in [0,32)
  const int n0 = ((k8 & 1) * 12 + (u >> 3)) * 128;  // n-tile in [0,24)
  const int wm = (w & 1) * 64, wn = (w >> 1) * 64;
  const int matid = n0 >> 10;
  const int nl0 = n0 & 1023;

  const int srow = t >> 3;
  const int gsrc = (t & 7) ^ (srow & 7);
  const ushort_t* Ag = Xbf + (size_t)(m0 + srow) * E_DIM + gsrc * 8;
  const ushort_t* Bg = Wqkv + (size_t)matid * E_DIM * E_DIM +
                       (size_t)(nl0 + srow) * E_DIM + gsrc * 8;

  f32x4 acc[4][4] = {};

  for (int kt = 0; kt < E_DIM / 64; ++kt) {
#pragma unroll
    for (int r = 0; r < 4; r++) {
      GLDS16(Ag + (size_t)r * 32 * E_DIM, As + r * 2048 + t * 8);
      GLDS16(Bg + (size_t)r * 32 * E_DIM, Bs + r * 2048 + t * 8);
    }
    Ag += 64; Bg += 64;
    __syncthreads();
#pragma unroll
    for (int kk = 0; kk < 2; kk++) {
      bf16x8 af[4], bfr[4];
      const int gs0 = (kk * 4 + quad) ^ (lr & 7);
#pragma unroll
      for (int i = 0; i < 4; i++) {
        af[i]  = *(const bf16x8*)(As + (wm + i * 16 + lr) * 64 + gs0 * 8);
        bfr[i] = *(const bf16x8*)(Bs + (wn + i * 16 + lr) * 64 + gs0 * 8);
      }
      if (matid < 2) {
#pragma unroll
        for (int i = 0; i < 4; i++)
#pragma unroll
          for (int j = 0; j < 4; j++)
            acc[i][j] = __builtin_amdgcn_mfma_f32_16x16x32_bf16(
                bfr[j], af[i], acc[i][j], 0, 0, 0);  // C^T
      } else {
#pragma unroll
        for (int i = 0; i < 4; i++)
#pragma unroll
          for (int j = 0; j < 4; j++)
            acc[i][j] = __builtin_amdgcn_mfma_f32_16x16x32_bf16(
                af[i], bfr[j], acc[i][j], 0, 0, 0);
      }
    }
    __syncthreads();
  }

  const float* bias_p = (matid == 0) ? bq : (matid == 1) ? bk : bv;
  ushort_t* Ls = smem;
  if (matid < 2) {
    // acc[i][j] = C^T tile: row n = wn+j*16+quad*4+r, col m = wm+i*16+lr.
    ushort_t* dst = (matid == 0) ? Qb : Kb;
    const float scl = (matid == 0) ? 0.18033688f : 1.0f;  // 0.125*log2e
#pragma unroll
    for (int j = 0; j < 4; j++) {
      const int nb = wn + j * 16 + quad * 4;
      float b0 = bias_p[nl0 + nb], b1 = bias_p[nl0 + nb + 1];
      float b2 = bias_p[nl0 + nb + 2], b3 = bias_p[nl0 + nb + 3];
#pragma unroll
      for (int i = 0; i < 4; i++) {
        const int m = wm + i * 16 + lr;
        bf16x4 pv;
        pv[0] = (__bf16)((acc[i][j][0] + b0) * scl);
        pv[1] = (__bf16)((acc[i][j][1] + b1) * scl);
        pv[2] = (__bf16)((acc[i][j][2] + b2) * scl);
        pv[3] = (__bf16)((acc[i][j][3] + b3) * scl);
        *(bf16x4*)(Ls + m * 128 + (((nb >> 3) ^ (m & 7)) * 8) + (nb & 7)) = pv;
      }
    }
    __syncthreads();
#pragma unroll
    for (int it = 0; it < 8; it++) {
      const int task = t + 256 * it;
      const int m = task >> 4, g = task & 15;
      uint4 val = *(const uint4*)(Ls + m * 128 + ((g ^ (m & 7)) * 8));
      const int s = m0 + m, bb = s >> 11, ss = s & 2047;
      const int cl = nl0 + g * 8, h = cl >> 6, dd = cl & 63;
      *(uint4*)(dst + ((size_t)((bb * H_NUM + h) * S_LEN + ss)) * HD_DIM + dd) =
          val;
    }
  } else {
    // acc[i][j] = C tile: row m(s), col n(d). Stage Ls[n][m], b64 along m.
#pragma unroll
    for (int j = 0; j < 4; j++) {
      const int n = wn + j * 16 + lr;
      const float bias = bias_p[nl0 + n];
#pragma unroll
      for (int i = 0; i < 4; i++) {
        const int mb = wm + i * 16 + quad * 4;
        bf16x4 pv;
        pv[0] = (__bf16)(acc[i][j][0] + bias);
        pv[1] = (__bf16)(acc[i][j][1] + bias);
        pv[2] = (__bf16)(acc[i][j][2] + bias);
        pv[3] = (__bf16)(acc[i][j][3] + bias);
        *(bf16x4*)(Ls + n * 128 + (((mb >> 3) ^ (n & 7)) * 8) + (mb & 7)) = pv;
      }
    }
    __syncthreads();
    const int n = t & 127, grp2 = t >> 7;
    ushort_t v[64];
#pragma unroll
    for (int c = 0; c < 8; c++)
      *(uint4*)(v + c * 8) =
          *(const uint4*)(Ls + n * 128 + (((grp2 * 8 + c) ^ (n & 7)) * 8));
    const int cl = nl0 + n, h = cl >> 6, dd = cl & 63;
    const int sgb = m0 + grp2 * 64, bb = sgb >> 11, ssb = sgb & 2047;
    ushort_t* dstp =
        Vt + ((size_t)((bb * H_NUM + h) * HD_DIM + dd)) * S_LEN + ssb;
#pragma unroll
    for (int q = 0; q < 8; q++) {
      ushort_t o8[8];
#pragma unroll
      for (int u2 = 0; u2 < 8; u2++)
        o8[u2] = v[16 * (u2 & 3) + 2 * q + (u2 >> 2)];
      *(uint4*)(dstp + q * 8) = *(const uint4*)o8;
    }
  }
}

// ---------------- flash attention (q-tile 128, 32 q-rows/wave) -------------
// grid: 512 blocks 1D. XCD swizzle: bid = bh%8 + 8*q + 128*(bh/8) so all
// 16 q-tiles of a bh share one XCD (K/V 2MB/XCD -> L2-resident).
__global__ __launch_bounds__(256) void attn(
    const ushort_t* __restrict__ Qb, const ushort_t* __restrict__ Kb,
    const ushort_t* __restrict__ Vt, ushort_t* __restrict__ Ctx) {
  __shared__ ushort_t Ks[64 * 64];  // swizzled K tile
  __shared__ ushort_t Vs[64 * 64];  // swizzled V^T tile
  __shared__ ushort_t Ps[128 * 72]; // P rows (stride 72); Q staged flat first
  const int t = threadIdx.x, w = t >> 6, lane = t & 63;
  const int quad = lane >> 4, lr = lane & 15;
  const int bid = blockIdx.x;
  const int bh = (bid >> 7) * 8 + (bid & 7);     // [0,32)
  const int q0 = ((bid >> 3) & 15) * 128;
  const ushort_t* Qg = Qb + ((size_t)bh * S_LEN + q0) * HD_DIM;
  const ushort_t* Kg = Kb + (size_t)bh * S_LEN * HD_DIM;
  const ushort_t* Vg = Vt + (size_t)bh * HD_DIM * S_LEN;

  const int srow = t >> 3;                // staging LDS row (32-row chunks)
  const int gsrc = (t & 7) ^ (srow & 7);  // swizzled source granule

  // prologue: stage Q (flat into Ps, 128x64), K tile 0, V tile 0
#pragma unroll
  for (int r = 0; r < 4; r++)
    GLDS16(Qg + (size_t)(r * 32 + srow) * HD_DIM + gsrc * 8,
           Ps + r * 2048 + t * 8);
#pragma unroll
  for (int r = 0; r < 2; r++) {
    GLDS16(Kg + (size_t)(r * 32 + srow) * HD_DIM + gsrc * 8,
           Ks + r * 2048 + t * 8);
    GLDS16(Vg + (size_t)(r * 32 + srow) * S_LEN + gsrc * 8,
           Vs + r * 2048 + t * 8);
  }
  __syncthreads();
  bf16x8 qf[2][2];  // [mt][kc]; wave-private rows [32w, 32w+32)
#pragma unroll
  for (int mt = 0; mt < 2; mt++)
#pragma unroll
    for (int kc = 0; kc < 2; kc++) {
      int gs = (kc * 4 + quad) ^ (lr & 7);
      qf[mt][kc] =
          *(const bf16x8*)(Ps + (w * 32 + mt * 16 + lr) * 64 + gs * 8);
    }

  bf16x8 ones;
#pragma unroll
  for (int e = 0; e < 8; e++) ones[e] = (__bf16)1.0f;

  f32x4 cacc[2][4] = {};
  f32x4 lsum[2] = {};

  for (int kt = 0; kt < S_LEN / 64; ++kt) {
    // --- QK: S' = (Q*0.125*log2e) @ K^T ---
    f32x4 sacc[2][4] = {};
#pragma unroll
    for (int nt = 0; nt < 4; nt++) {
#pragma unroll
      for (int kc = 0; kc < 2; kc++) {
        int gs = (kc * 4 + quad) ^ (lr & 7);
        bf16x8 kf = *(const bf16x8*)(Ks + (nt * 16 + lr) * 64 + gs * 8);
        sacc[0][nt] = __builtin_amdgcn_mfma_f32_16x16x32_bf16(
            qf[0][kc], kf, sacc[0][nt], 0, 0, 0);
        sacc[1][nt] = __builtin_amdgcn_mfma_f32_16x16x32_bf16(
            qf[1][kc], kf, sacc[1][nt], 0, 0, 0);
      }
    }
    __syncthreads();  // barrier A: K reads done; drains prev V prefetch

    const int kn = (kt + 1) & (S_LEN / 64 - 1);
    // prefetch next K (hidden behind exp + PV)
#pragma unroll
    for (int r = 0; r < 2; r++)
      GLDS16(Kg + (size_t)(kn * 64 + r * 32 + srow) * HD_DIM + gsrc * 8,
             Ks + r * 2048 + t * 8);

    // --- softmax numerator: p = exp2(s'), packed b64 into wave-private Ps
#pragma unroll
    for (int mt = 0; mt < 2; mt++) {
#pragma unroll
      for (int i = 0; i < 4; i++) {
        float p0 = EXP2(sacc[mt][0][i]);
        float p1 = EXP2(sacc[mt][1][i]);
        float p2 = EXP2(sacc[mt][2][i]);
        float p3 = EXP2(sacc[mt][3][i]);
        bf16x4 pv;
        pv[0] = (__bf16)p0; pv[1] = (__bf16)p1;
        pv[2] = (__bf16)p2; pv[3] = (__bf16)p3;
        int row = w * 32 + mt * 16 + quad * 4 + i;
        *(bf16x4*)(Ps + row * 72 + lr * 4) = pv;
      }
    }

    // --- PV + MFMA row-sum; vf shared across mt ---
#pragma unroll
    for (int kc = 0; kc < 2; kc++) {
      int gs = (kc * 4 + quad) ^ (lr & 7);
      bf16x8 vf[4];
#pragma unroll
      for (int dt = 0; dt < 4; dt++)
        vf[dt] = *(const bf16x8*)(Vs + (dt * 16 + lr) * 64 + gs * 8);
#pragma unroll
      for (int mt = 0; mt < 2; mt++) {
        bf16x8 pf = *(const bf16x8*)(Ps + (w * 32 + mt * 16 + lr) * 72 +
                                     kc * 32 + quad * 8);
        lsum[mt] =
            __builtin_amdgcn_mfma_f32_16x16x32_bf16(pf, ones, lsum[mt], 0, 0, 0);
#pragma unroll
        for (int dt = 0; dt < 4; dt++)
          cacc[mt][dt] = __builtin_amdgcn_mfma_f32_16x16x32_bf16(
              pf, vf[dt], cacc[mt][dt], 0, 0, 0);
      }
    }
    __syncthreads();  // barrier B: V reads done; drains this iter's K prefetch

    // prefetch next V (hidden behind loop-back + next QK)
#pragma unroll
    for (int r = 0; r < 2; r++)
      GLDS16(Vg + (size_t)(r * 32 + srow) * S_LEN + kn * 64 + gsrc * 8,
             Vs + r * 2048 + t * 8);
  }

  // epilogue: lsum holds full row sums (identical across the 16 lanes)
#pragma unroll
  for (int mt = 0; mt < 2; mt++) {
#pragma unroll
    for (int i = 0; i < 4; i++) {
      float inv = 1.0f / lsum[mt][i];
      int srow2 = q0 + w * 32 + mt * 16 + quad * 4 + i;
#pragma unroll
      for (int dt = 0; dt < 4; dt++)
        Ctx[((size_t)bh * S_LEN + srow2) * HD_DIM + dt * 16 + lr] =
            f2bf(cacc[mt][dt][i] * inv);
    }
  }
}

// ---------------- output projection gemm (64x64 tiles, BK=64) ----------------
// grid: 1024 blocks 1D. XCD swizzle: xcd k owns m-tiles [8k,8k+8) x all 16 n
// (A 1MB + Wo 2MB per XCD -> L2-resident).
__global__ __launch_bounds__(256) void gemm_out(
    const ushort_t* __restrict__ Cb, const ushort_t* __restrict__ Wob,
    const float* __restrict__ bo, float* __restrict__ out) {
  __shared__ ushort_t As[64 * 64];
  __shared__ ushort_t Bs[64 * 64];
  const int t = threadIdx.x;
  const int w = t >> 6, lane = t & 63, quad = lane >> 4, lr = lane & 15;
  const int bid = blockIdx.x;
  const int k8 = bid & 7, u = bid >> 3;  // u in [0,128)
  const int m0 = (k8 * 8 + (u & 7)) * 64;  // m-tile in [0,64)
  const int n0 = (u >> 3) * 64;            // n-tile in [0,16)
  const int wm = (w & 1) * 32, wn = (w >> 1) * 32;

  const int srow = t >> 3;
  const int gsrc = (t & 7) ^ (srow & 7);
  const ushort_t* Ag = Cb + (size_t)(m0 + srow) * E_DIM + gsrc * 8;
  const ushort_t* Bg = Wob + (size_t)(n0 + srow) * E_DIM + gsrc * 8;

  f32x4 acc[2][2] = {};

  for (int kt = 0; kt < E_DIM / 64; ++kt) {
#pragma unroll
    for (int r = 0; r < 2; r++) {
      GLDS16(Ag + (size_t)r * 32 * E_DIM, As + r * 2048 + t * 8);
      GLDS16(Bg + (size_t)r * 32 * E_DIM, Bs + r * 2048 + t * 8);
    }
    Ag += 64; Bg += 64;
    __syncthreads();
#pragma unroll
    for (int kk = 0; kk < 2; kk++) {
      bf16x8 af[2], bfr[2];
      const int gs0 = (kk * 4 + quad) ^ (lr & 7);
#pragma unroll
      for (int i = 0; i < 2; i++) {
        af[i]  = *(const bf16x8*)(As + (wm + i * 16 + lr) * 64 + gs0 * 8);
        bfr[i] = *(const bf16x8*)(Bs + (wn + i * 16 + lr) * 64 + gs0 * 8);
      }
#pragma unroll
      for (int i = 0; i < 2; i++)
#pragma unroll
        for (int j = 0; j < 2; j++)
          acc[i][j] = __builtin_amdgcn_mfma_f32_16x16x32_bf16(
              af[i], bfr[j], acc[i][j], 0, 0, 0);
    }
    __syncthreads();
  }

#pragma unroll
  for (int j = 0; j < 2; j++) {
    int col = n0 + wn + j * 16 + lr;
    float bias = bo[col];
#pragma unroll
    for (int i = 0; i < 2; i++) {
#pragma unroll
      for (int r = 0; r < 4; r++) {
        int row = m0 + wm + i * 16 + quad * 4 + r;
        out[(size_t)row * E_DIM + col] = acc[i][j][r] + bias;
      }
    }
  }
}

// ---------------- launch ----------------
extern "C" void kernel_launch(void* const* d_in, const int* in_sizes, int n_in,
                              void* d_out, int out_size, void* d_ws,
                              size_t ws_size, hipStream_t stream) {
  const float* X  = (const float*)d_in[0];
  const float* bq = (const float*)d_in[2];
  const float* bk = (const float*)d_in[4];
  const float* bv = (const float*)d_in[6];
  const float* Wo = (const float*)d_in[7];
  const float* bo = (const float*)d_in[8];
  float* out = (float*)d_out;

  char* ws = (char*)d_ws;
  ushort_t* Xbf  = (ushort_t*)(ws);                       // 8 MB
  ushort_t* Wqkv = (ushort_t*)(ws + ((size_t)8 << 20));   // 6 MB
  ushort_t* Wob  = (ushort_t*)(ws + ((size_t)14 << 20));  // 2 MB
  ushort_t* Qb   = (ushort_t*)(ws + ((size_t)16 << 20));  // 8 MB
  ushort_t* Kb   = (ushort_t*)(ws + ((size_t)24 << 20));  // 8 MB
  ushort_t* Vt   = (ushort_t*)(ws + ((size_t)32 << 20));  // 8 MB
  ushort_t* Cb   = (ushort_t*)(ws + ((size_t)40 << 20));  // 8 MB (48 MB total)

  cvt_all<<<8192, 256, 0, stream>>>(X, (const float*)d_in[1],
                                    (const float*)d_in[3],
                                    (const float*)d_in[5], Wo, Xbf, Wqkv, Wob);

  gemm_qkv<<<768, 256, 0, stream>>>(Xbf, Wqkv, bq, bk, bv, Qb, Kb, Vt);
  attn<<<512, 256, 0, stream>>>(Qb, Kb, Vt, Cb);
  gemm_out<<<1024, 256, 0, stream>>>(Cb, Wob, bo, out);
}